// Round 9
// baseline (175.986 us; speedup 1.0000x reference)
//
#include <hip/hip_runtime.h>
#include <hip/hip_bf16.h>

// Problem constants: T=1024, B=2, E=1024, H=16, D=64, R=2*T-1
#define TT 1024
#define BB 2
#define EE 1024
#define HH 16
#define DD 64
#define RR 2047
#define TB (TT * BB)   // 2048
#define E3 (3 * EE)    // 3072

typedef __attribute__((ext_vector_type(4))) float f32x4;
typedef __attribute__((ext_vector_type(8))) short s16x8;

static __device__ __forceinline__ short f2bf(float x) {
  unsigned u = __builtin_bit_cast(unsigned, x);
  unsigned r = (u + 0x7FFFu + ((u >> 16) & 1u)) >> 16;
  return (short)r;
}
static __device__ __forceinline__ float bf2f(short x) {
  unsigned u = ((unsigned)(unsigned short)x) << 16;
  return __builtin_bit_cast(float, u);
}
static __device__ __forceinline__ float bperm(int idx, float v) {
  return __builtin_bit_cast(float,
      __builtin_amdgcn_ds_bpermute(idx, __builtin_bit_cast(int, v)));
}

// ---------------------------------------------------------------------------
// Fused fp32 -> bf16 convert for all 5 tensors (one launch).
// ---------------------------------------------------------------------------
__global__ __launch_bounds__(256) void cvt_all(
    const float* __restrict__ x, const float* __restrict__ in_w,
    const float* __restrict__ pos, const float* __restrict__ pos_w,
    const float* __restrict__ out_w,
    short* __restrict__ xb, short* __restrict__ inwb, short* __restrict__ posb,
    short* __restrict__ poswb, short* __restrict__ outwb) {
  const long M1 = 1 << 20;
  long off = (long)(blockIdx.x * 256 + threadIdx.x) * 8;
  const float* src; short* dst; long nsrc;
  if (off < 2 * M1)      { src = x;     dst = xb;    nsrc = 2 * M1; }
  else if (off < 5 * M1) { off -= 2 * M1; src = in_w;  dst = inwb;  nsrc = 3 * M1; }
  else if (off < 7 * M1) { off -= 5 * M1; src = pos;   dst = posb;  nsrc = (long)RR * EE; }
  else if (off < 8 * M1) { off -= 7 * M1; src = pos_w; dst = poswb; nsrc = M1; }
  else                   { off -= 8 * M1; src = out_w; dst = outwb; nsrc = M1; }
  s16x8 o;
  if (off + 8 <= nsrc) {
    f32x4 a = *(const f32x4*)&src[off];
    f32x4 c = *(const f32x4*)&src[off + 4];
    #pragma unroll
    for (int j = 0; j < 4; ++j) { o[j] = f2bf(a[j]); o[4 + j] = f2bf(c[j]); }
  } else {
    #pragma unroll
    for (int j = 0; j < 8; ++j) o[j] = 0;
  }
  *(s16x8*)&dst[off] = o;
}

// ---------------------------------------------------------------------------
// bf16 MFMA GEMM (m97 structure): C[M,N] = A[M,K] @ W[N,K]^T + bias[N]
// ---------------------------------------------------------------------------
#define GBM 128
#define GBN 128
#define GBK 32

template <int OUT_BF16>
__global__ __launch_bounds__(256) void gemm_bf16_mfma(
    const short* __restrict__ A, const short* __restrict__ W,
    const float* __restrict__ bias, void* __restrict__ Cout,
    int M, int N, int K) {
  __shared__ __align__(16) short lA[2][GBM * GBK];
  __shared__ __align__(16) short lB[2][GBN * GBK];

  const int tid = threadIdx.x;
  const int lane = tid & 63;
  const int wv = tid >> 6;
  const int g = lane >> 4, cc = lane & 15;
  const int wr = wv >> 1, wc = wv & 1;
  const int m0 = blockIdx.y * GBM, n0 = blockIdx.x * GBN;

  f32x4 acc[4][4];
  #pragma unroll
  for (int i = 0; i < 4; ++i)
    #pragma unroll
    for (int j = 0; j < 4; ++j) acc[i][j] = (f32x4){0.f, 0.f, 0.f, 0.f};

#define STAGE_TILE(kk_, buf_)                                                  \
  {                                                                            \
    _Pragma("unroll")                                                          \
    for (int s = 0; s < 2; ++s) {                                              \
      int c = s * 256 + tid;                                                   \
      int row = c >> 2, slot = c & 3;                                          \
      int k8 = slot ^ (row & 3);                                               \
      __builtin_amdgcn_global_load_lds(                                        \
          (const __attribute__((address_space(1))) void*)(A + (size_t)(m0 + row) * K + (kk_) + k8 * 8), \
          (__attribute__((address_space(3))) void*)&lA[buf_][c * 8], 16, 0, 0);\
      __builtin_amdgcn_global_load_lds(                                        \
          (const __attribute__((address_space(1))) void*)(W + (size_t)(n0 + row) * K + (kk_) + k8 * 8), \
          (__attribute__((address_space(3))) void*)&lB[buf_][c * 8], 16, 0, 0);\
    }                                                                          \
  }

  int cur = 0;
  const int nt = K / GBK;
  STAGE_TILE(0, 0);

  #pragma unroll 1
  for (int t = 0; t < nt; ++t) {
    __syncthreads();
    if (t + 1 < nt) STAGE_TILE((t + 1) * GBK, cur ^ 1);

    s16x8 af[4], bf[4];
    #pragma unroll
    for (int mt = 0; mt < 4; ++mt) {
      int row = 64 * wr + 16 * mt + cc;
      af[mt] = *(const s16x8*)&lA[cur][row * GBK + ((g ^ (row & 3)) * 8)];
    }
    #pragma unroll
    for (int ntc = 0; ntc < 4; ++ntc) {
      int col = 64 * wc + 16 * ntc + cc;
      bf[ntc] = *(const s16x8*)&lB[cur][col * GBK + ((g ^ (col & 3)) * 8)];
    }
    #pragma unroll
    for (int mt = 0; mt < 4; ++mt)
      #pragma unroll
      for (int ntc = 0; ntc < 4; ++ntc)
        acc[mt][ntc] = __builtin_amdgcn_mfma_f32_16x16x32_bf16(
            af[mt], bf[ntc], acc[mt][ntc], 0, 0, 0);
    cur ^= 1;
  }
#undef STAGE_TILE

  #pragma unroll
  for (int ntc = 0; ntc < 4; ++ntc) {
    int col = n0 + 64 * wc + 16 * ntc + cc;
    float bv = bias[col];
    #pragma unroll
    for (int mt = 0; mt < 4; ++mt)
      #pragma unroll
      for (int r = 0; r < 4; ++r) {
        int rowg = m0 + 64 * wr + 16 * mt + 4 * g + r;
        float val = acc[mt][ntc][r] + bv;
        if (OUT_BF16)
          ((short*)Cout)[(size_t)rowg * N + col] = f2bf(val);
        else
          ((float*)Cout)[(size_t)rowg * N + col] = val;
      }
  }
}

// ---------------------------------------------------------------------------
// MFMA flash attention — R4 per-wave pattern, q-co-location for L2 reuse.
//   grid (T/32=32, B*H=32); 4 waves/block = (qh,kh): wave handles 16 q-rows
//   (iq0 + 16*qh) x 512 keys [512*kh, 512*kh+512) as 16 sequential 32-key
//   tiles with private online softmax — EXACTLY R4's proven loop. The two
//   qh-waves of the same kh read identical K/V addresses nearly in-phase
//   (same CU, no barriers) -> L1/L2 temporal reuse halves HBM fetch/q-row.
//   Merge pairs (qh,0)+(qh,1) via LDS; one barrier total.
//   score[i,j] = qw_i.k_j + qr_i.p[j-i+1023]  (1/8 scale folded in)
//   BD gather via ds_bpermute: S[ct][r] += Btilde[ii][16ct+cc+15-ii].
// LDS arena (23040 B), wave-private during loop:
//   sV[w]  = arena + w*4352          : short[32][68]  (loop; merge sO aliases)
//   sPm[w] = arena + 17408 + w*1280  : short[16][40]
//   sML    = arena + 22528           : float[4][2][16]
// ---------------------------------------------------------------------------
__global__ __launch_bounds__(256, 4) void rel_attn_mfma6(
    const short* __restrict__ qkvb,  // [TB][3E] bf16
    const short* __restrict__ pb,    // [2048][E] bf16 (row 2047 zeroed)
    const float* __restrict__ rwb,   // [H*D]
    const float* __restrict__ rrb,   // [H*D]
    short* __restrict__ ctxb) {      // [TB][E] bf16
  __shared__ __align__(16) char arena[23040];

  const int tid = threadIdx.x;
  const int wv = tid >> 6;
  const int qh = wv >> 1, kh2 = wv & 1;
  const int lane = tid & 63;
  const int g = lane >> 4;      // 0..3
  const int cc = lane & 15;     // 0..15
  const int iq0 = blockIdx.x * 32 + qh * 16;
  const int bh = blockIdx.y;
  const int b = bh >> 4, h = bh & 15;
  const int hoff = h * DD;

  short* sV  = (short*)(arena + wv * 4352);            // [32][68]
  short* sPm = (short*)(arena + 17408 + wv * 1280);    // [16][40]

  // ---- Q fragments: row = cc (q row iq0+cc), k-pack d = 32*kh + 8*g ----
  s16x8 qw[2], qr[2];
  #pragma unroll
  for (int kh = 0; kh < 2; ++kh) {
    const int d0 = 32 * kh + 8 * g;
    const short* qp = qkvb + (size_t)((iq0 + cc) * BB + b) * E3 + hoff + d0;
    const float* rw = rwb + hoff + d0;
    const float* rr = rrb + hoff + d0;
    s16x8 qv = *(const s16x8*)qp;
    #pragma unroll
    for (int j = 0; j < 8; ++j) {
      float q = bf2f(qv[j]);
      qw[kh][j] = f2bf((q + rw[j]) * 0.125f);
      qr[kh][j] = f2bf((q + rr[j]) * 0.125f);
    }
  }

  f32x4 O[4];
  #pragma unroll
  for (int dt = 0; dt < 4; ++dt) O[dt] = (f32x4){0.f, 0.f, 0.f, 0.f};
  float mrun[4], lrun[4];
  #pragma unroll
  for (int r = 0; r < 4; ++r) { mrun[r] = -1e30f; lrun[r] = 0.f; }

  #pragma unroll 1
  for (int t = 0; t < 16; ++t) {
    const int j0 = 512 * kh2 + 32 * t;   // this wave's key tile base

    // ---- stage V tile [32][64] -> sV [32][68] (wave-private) ----
    #pragma unroll
    for (int c = 0; c < 4; ++c) {
      int id = c * 64 + lane;
      int row = id >> 3, c8 = id & 7;
      const short* src = qkvb + (size_t)((j0 + row) * BB + b) * E3 + 2 * EE + hoff + c8 * 8;
      *(s16x8*)&sV[row * 68 + c8 * 8] = *(const s16x8*)src;
    }

    // ---- AC: S[ct] = qw . K^T, K fragments direct from global ----
    s16x8 kf[2][2];
    #pragma unroll
    for (int ct = 0; ct < 2; ++ct)
      #pragma unroll
      for (int kh = 0; kh < 2; ++kh)
        kf[ct][kh] = *(const s16x8*)(qkvb + (size_t)((j0 + 16 * ct + cc) * BB + b) * E3 + EE + hoff + 32 * kh + 8 * g);

    f32x4 S[2];
    #pragma unroll
    for (int ct = 0; ct < 2; ++ct) {
      S[ct] = (f32x4){0.f, 0.f, 0.f, 0.f};
      #pragma unroll
      for (int kh = 0; kh < 2; ++kh)
        S[ct] = __builtin_amdgcn_mfma_f32_16x16x32_bf16(qw[kh], kf[ct][kh], S[ct], 0, 0, 0);
    }

    // ---- BD: Btilde = qr . pband^T (3 ut tiles), band direct from global ----
    const int gmin = j0 - iq0 + 1008;
    f32x4 bt[3];
    #pragma unroll
    for (int ut = 0; ut < 3; ++ut) {
      const int prl = gmin + 16 * ut + cc;   // in [0, 2047]; row 2047 zeroed
      bt[ut] = (f32x4){0.f, 0.f, 0.f, 0.f};
      #pragma unroll
      for (int kh = 0; kh < 2; ++kh) {
        s16x8 pf = *(const s16x8*)(pb + (size_t)prl * EE + hoff + 32 * kh + 8 * g);
        bt[ut] = __builtin_amdgcn_mfma_f32_16x16x32_bf16(qr[kh], pf, bt[ut], 0, 0, 0);
      }
    }
    // gather: S[ct][r] += Btilde[ii=4g+r][16ct + cc+15-ii] via bpermute.
    #pragma unroll
    for (int r = 0; r < 4; ++r) {
      const int usub = cc + 15 - 4 * g - r;            // 0..30
      const int idx = ((lane & 48) | (usub & 15)) << 2;
      const float va = bperm(idx, bt[0][r]);
      const float vb = bperm(idx, bt[1][r]);
      const float vc = bperm(idx, bt[2][r]);
      const bool hi = usub >= 16;
      S[0][r] += hi ? vb : va;
      S[1][r] += hi ? vc : vb;
    }

    // ---- online softmax (rows = 4g+r, cols spread over cc and ct) ----
    float mx[4];
    #pragma unroll
    for (int r = 0; r < 4; ++r) mx[r] = fmaxf(S[0][r], S[1][r]);
    #pragma unroll
    for (int msk = 1; msk < 16; msk <<= 1)
      #pragma unroll
      for (int r = 0; r < 4; ++r) mx[r] = fmaxf(mx[r], __shfl_xor(mx[r], msk, 64));
    float f[4], sm[4];
    #pragma unroll
    for (int r = 0; r < 4; ++r) {
      float mn = fmaxf(mrun[r], mx[r]);
      f[r] = __expf(mrun[r] - mn);
      mrun[r] = mn;
      S[0][r] = __expf(S[0][r] - mn);
      S[1][r] = __expf(S[1][r] - mn);
      sm[r] = S[0][r] + S[1][r];
    }
    #pragma unroll
    for (int msk = 1; msk < 16; msk <<= 1)
      #pragma unroll
      for (int r = 0; r < 4; ++r) sm[r] += __shfl_xor(sm[r], msk, 64);
    #pragma unroll
    for (int r = 0; r < 4; ++r) lrun[r] = lrun[r] * f[r] + sm[r];
    #pragma unroll
    for (int dt = 0; dt < 4; ++dt)
      #pragma unroll
      for (int r = 0; r < 4; ++r) O[dt][r] *= f[r];

    // ---- P to A-fragment layout via wave-private LDS ----
    #pragma unroll
    for (int ct = 0; ct < 2; ++ct)
      #pragma unroll
      for (int r = 0; r < 4; ++r)
        sPm[(4 * g + r) * 40 + 16 * ct + cc] = f2bf(S[ct][r]);

    s16x8 pa = *(const s16x8*)&sPm[cc * 40 + 8 * g];

    // ---- V^T fragments (scalar transpose reads) + PV ----
    s16x8 vf[4];
    #pragma unroll
    for (int dt = 0; dt < 4; ++dt)
      #pragma unroll
      for (int jj = 0; jj < 8; ++jj)
        vf[dt][jj] = sV[(8 * g + jj) * 68 + 16 * dt + cc];
    #pragma unroll
    for (int dt = 0; dt < 4; ++dt)
      O[dt] = __builtin_amdgcn_mfma_f32_16x16x32_bf16(pa, vf[dt], O[dt], 0, 0, 0);
  }

  // ---- merge pairs (qh,kh=0)+(qh,kh=1) via LDS ----
  float* sOw = (float*)(arena + wv * 4352);      // [16][68] f32, aliases own sV
  #pragma unroll
  for (int dt = 0; dt < 4; ++dt)
    #pragma unroll
    for (int r = 0; r < 4; ++r)
      sOw[(4 * g + r) * 68 + 16 * dt + cc] = O[dt][r];
  float* sML = (float*)(arena + 22528);          // [w][2][16]
  if (cc == 0) {
    #pragma unroll
    for (int r = 0; r < 4; ++r) {
      sML[wv * 32 + (4 * g + r)] = mrun[r];
      sML[wv * 32 + 16 + (4 * g + r)] = lrun[r];
    }
  }
  __syncthreads();

  // 256 threads cover 32 rows x 64 cols, 8 cols/thread
  const int ii = tid >> 3;            // 0..31
  const int ii_l = ii & 15;
  const int w0 = (ii >> 4) * 2, w1 = w0 + 1;
  const int c0 = (tid & 7) * 8;
  const float m0 = sML[w0 * 32 + ii_l], l0 = sML[w0 * 32 + 16 + ii_l];
  const float m1 = sML[w1 * 32 + ii_l], l1 = sML[w1 * 32 + 16 + ii_l];
  const float M = fmaxf(m0, m1);
  const float f0 = __expf(m0 - M), f1 = __expf(m1 - M);
  const float rinv = 1.0f / (f0 * l0 + f1 * l1);
  const float* sO0 = (const float*)(arena + w0 * 4352);
  const float* sO1 = (const float*)(arena + w1 * 4352);
  short* dst = ctxb + (size_t)((blockIdx.x * 32 + ii) * BB + b) * EE + hoff + c0;
  #pragma unroll
  for (int jj = 0; jj < 8; ++jj) {
    const float val = (f0 * sO0[ii_l * 68 + c0 + jj] + f1 * sO1[ii_l * 68 + c0 + jj]) * rinv;
    dst[jj] = f2bf(val);
  }
}

// ---------------------------------------------------------------------------
extern "C" void kernel_launch(void* const* d_in, const int* in_sizes, int n_in,
                              void* d_out, int out_size, void* d_ws, size_t ws_size,
                              hipStream_t stream) {
  const float* x      = (const float*)d_in[0];
  const float* pos    = (const float*)d_in[1];
  const float* in_w   = (const float*)d_in[2];
  const float* in_b   = (const float*)d_in[3];
  const float* pos_w  = (const float*)d_in[4];
  const float* pos_b  = (const float*)d_in[5];
  const float* out_w  = (const float*)d_in[6];
  const float* out_b  = (const float*)d_in[7];
  const float* r_w    = (const float*)d_in[8];
  const float* r_r    = (const float*)d_in[9];
  float* out = (float*)d_out;

  const size_t M1 = 1024 * 1024;
  short* xb    = (short*)d_ws;        // 2M
  short* inwb  = xb    + 2 * M1;      // 3M
  short* posb  = inwb  + 3 * M1;      // 2M (2048 rows, row 2047 zeroed)
  short* poswb = posb  + 2 * M1;      // 1M
  short* outwb = poswb + 1 * M1;      // 1M
  short* qkvb  = outwb + 1 * M1;      // 6M
  short* pb    = qkvb  + 6 * M1;      // 2M
  short* ctxb  = pb    + 2 * M1;      // 2M

  cvt_all<<<dim3(4608), dim3(256), 0, stream>>>(
      x, in_w, pos, pos_w, out_w, xb, inwb, posb, poswb, outwb);

  gemm_bf16_mfma<1><<<dim3(E3 / GBN, TB / GBM), dim3(256), 0, stream>>>(
      xb, inwb, in_b, qkvb, TB, E3, EE);

  gemm_bf16_mfma<1><<<dim3(EE / GBN, 2048 / GBM), dim3(256), 0, stream>>>(
      posb, poswb, pos_b, pb, 2048, EE, EE);

  rel_attn_mfma6<<<dim3(TT / 32, BB * HH), dim3(256), 0, stream>>>(
      qkvb, pb, r_w, r_r, ctxb);

  gemm_bf16_mfma<0><<<dim3(EE / GBN, TB / GBM), dim3(256), 0, stream>>>(
      ctxb, outwb, out_b, out, TB, EE, EE);
}